// Round 9
// baseline (19.109 us; speedup 1.0000x reference)
//
#include <hip/hip_runtime.h>

typedef _Float16 half2v __attribute__((ext_vector_type(2)));
typedef _Float16 half8v __attribute__((ext_vector_type(8)));
typedef float floatx4 __attribute__((ext_vector_type(4)));

#define NBATCH 1024
#define NKSPLIT 256
#define KPW 8             // k-steps (of 32 rules) per ksplit
#define NMTILE 16         // 16 mtiles x 64 batches
#define MSPAD 36          // LDS row stride (floats): 16B-aligned, 2-way-bank (free)

__device__ __forceinline__ float sel4(float a0, float a1, float a2, float a3, int d) {
  float r = (d == 1) ? a1 : a0;
  r = (d == 2) ? a2 : r;
  r = (d == 3) ? a3 : r;
  return r;
}

__device__ __forceinline__ half2v cvt2h(float a, float b) {
  return __builtin_bit_cast(half2v, __builtin_amdgcn_cvt_pkrtz(a, b));
}

// ---- main: 512-thread block = 8 waves = 8 consecutive ksplits of one mtile.
// Block cooperatively computes the mtile's 64x32 memberships once into LDS.
// grid = 16 mtiles x 32 = 512 blocks, 2 blocks/CU -> 16 waves/CU (4/SIMD).
__global__ __launch_bounds__(512, 4) void anfis_main(
    const float* __restrict__ x, const float* __restrict__ mu,
    const float* __restrict__ sigma, const float* __restrict__ cw,
    const float* __restrict__ cb, float* __restrict__ part) {
  const int bid = blockIdx.x;
  const int mtile = bid >> 5;            // 0..15
  const int kg = bid & 31;               // 0..31
  const int t = threadIdx.x;
  const int w = t >> 6;                  // wave 0..7
  const int l = t & 63;
  const int g = l >> 4, col = l & 15;
  const int u = g & 1, h = g >> 1;       // u = d6 high bit, h = d5 low bit
  const int ksplit = kg * 8 + w;         // 0..255 = d0 d1 d2 d3
  const int d0 = (ksplit >> 6) & 3, d1 = (ksplit >> 4) & 3;
  const int d2 = (ksplit >> 2) & 3, d3 = ksplit & 3;
  const int b0 = mtile * 64;
  const int r0 = ksplit * (KPW * 32) + g * 8;

  // per-lane B gather base + strides. col>8 lanes mirror col==8 (cb broadcast);
  // their C columns are discarded by xc=0 in the epilogue.
  const bool isw = (col < 8);
  const float* gp = isw ? (cw + (size_t)r0 * 8 + col) : (cb + r0);
  const int es = isw ? 8 : 1;
  const int ks = isw ? 256 : 32;

  // prefetch first 4 k-steps of B (latency hides under the exp/LDS prologue)
  float fv[4][8];
#pragma unroll
  for (int kk = 0; kk < 4; ++kk)
#pragma unroll
    for (int e = 0; e < 8; ++e)
      fv[kk][e] = gp[kk * ks + e * es];

  // ---- cooperative membership fill: 2048 exps / 512 threads = 4 each
  __shared__ float msL[64][MSPAD];
  {
    const int bt = t >> 3;               // batch 0..63
    const int j0 = (t & 7) * 4;          // 4 js per thread
#pragma unroll
    for (int j = 0; j < 4; ++j) {
      const int jj = j0 + j;
      const int i = jj >> 2;
      float s_ = fabsf(sigma[jj]) + 1e-5f;       // uniform -> s_load
      float rs = __builtin_amdgcn_rcpf(s_);
      float nv = -0.5f * rs * rs;
      float d = x[(b0 + bt) * 8 + i] - mu[jj];   // mu uniform
      msL[bt][jj] = __expf(d * d * nv);
    }
  }
  __syncthreads();

  // ---- per-rowblock context from LDS
  half2v tab[4][4];
  float pA[4], pB[4];      // pre * m5[{0,1}*2+h]
  floatx4 m4v[4];
#pragma unroll
  for (int rb = 0; rb < 4; ++rb) {
    const float* row = msL[rb * 16 + col];
    floatx4 m0 = *(const floatx4*)(row + 0);
    floatx4 m1 = *(const floatx4*)(row + 4);
    floatx4 m2 = *(const floatx4*)(row + 8);
    floatx4 m3 = *(const floatx4*)(row + 12);
    floatx4 m4 = *(const floatx4*)(row + 16);
    floatx4 m5 = *(const floatx4*)(row + 20);
    floatx4 m6 = *(const floatx4*)(row + 24);
    floatx4 m7 = *(const floatx4*)(row + 28);
    float pre = sel4(m0[0], m0[1], m0[2], m0[3], d0) *
                sel4(m1[0], m1[1], m1[2], m1[3], d1) *
                sel4(m2[0], m2[1], m2[2], m2[3], d2) *
                sel4(m3[0], m3[1], m3[2], m3[3], d3);
    float m5A = h ? m5[1] : m5[0];
    float m5B = h ? m5[3] : m5[2];
    float m60 = u ? m6[2] : m6[0];
    float m61 = u ? m6[3] : m6[1];
    tab[rb][0] = cvt2h(m60 * m7[0], m60 * m7[1]);
    tab[rb][1] = cvt2h(m60 * m7[2], m60 * m7[3]);
    tab[rb][2] = cvt2h(m61 * m7[0], m61 * m7[1]);
    tab[rb][3] = cvt2h(m61 * m7[2], m61 * m7[3]);
    pA[rb] = pre * m5A;
    pB[rb] = pre * m5B;
    m4v[rb] = m4;
  }

  floatx4 acc[4];
#pragma unroll
  for (int rb = 0; rb < 4; ++rb) acc[rb] = (floatx4){0.f, 0.f, 0.f, 0.f};

#pragma unroll
  for (int kk = 0; kk < KPW; ++kk) {
    const int j4 = kk >> 1, j5 = kk & 1;   // d4 = j4, d5 = j5*2 + h
    half2v b01 = cvt2h(fv[kk & 3][0], fv[kk & 3][1]);
    half2v b23 = cvt2h(fv[kk & 3][2], fv[kk & 3][3]);
    half2v b45 = cvt2h(fv[kk & 3][4], fv[kk & 3][5]);
    half2v b67 = cvt2h(fv[kk & 3][6], fv[kk & 3][7]);
    half8v b8 = {b01.x, b01.y, b23.x, b23.y, b45.x, b45.y, b67.x, b67.y};
    if (kk + 4 < KPW) {
#pragma unroll
      for (int e = 0; e < 8; ++e)
        fv[kk & 3][e] = gp[(kk + 4) * ks + e * es];
    }
#pragma unroll
    for (int rb = 0; rb < 4; ++rb) {
      float p5 = (j5 ? pB[rb] : pA[rb]) * m4v[rb][j4];   // j4 compile-time
      _Float16 ph = (_Float16)p5;
      half2v ppv = {ph, ph};
      half2v a0 = ppv * tab[rb][0], a1 = ppv * tab[rb][1],
             a2 = ppv * tab[rb][2], a3 = ppv * tab[rb][3];
      half8v a8 = {a0.x, a0.y, a1.x, a1.y, a2.x, a2.y, a3.x, a3.y};
      acc[rb] = __builtin_amdgcn_mfma_f32_16x16x32_f16(a8, b8, acc[rb], 0, 0, 0);
    }
  }

  // epilogue: C[row=g*4+i][col], fold x, reduce over 16 cols -> part
#pragma unroll
  for (int rb = 0; rb < 4; ++rb) {
#pragma unroll
    for (int i = 0; i < 4; ++i) {
      int bb = b0 + rb * 16 + g * 4 + i;
      float xc = 0.0f;
      if (col < 8) xc = x[bb * 8 + col];
      else if (col == 8) xc = 1.0f;
      float v = acc[rb][i] * xc;
      v += __shfl_xor(v, 1);
      v += __shfl_xor(v, 2);
      v += __shfl_xor(v, 4);
      v += __shfl_xor(v, 8);
      if (col == 0) part[ksplit * NBATCH + bb] = v;
    }
  }
}

// ---- final: reduce 256 k-splits per batch + analytic separable denominator.
__global__ __launch_bounds__(256) void anfis_final(
    const float* __restrict__ part, const float* __restrict__ x,
    const float* __restrict__ mu, const float* __restrict__ sigma,
    float* __restrict__ out) {
  const int t = threadIdx.x;
  const int bloc = t & 15;
  const int chunk = t >> 4;     // 16 chunks x 16 splits
  const int b = blockIdx.x * 16 + bloc;

  float s = 0.0f;
#pragma unroll
  for (int j = 0; j < 16; ++j)
    s += part[(chunk * 16 + j) * NBATCH + b];

  __shared__ float red[16][17];
  red[chunk][bloc] = s;
  __syncthreads();

  if (t < 16) {
    const int bb = blockIdx.x * 16 + t;
    float tot = 0.0f;
#pragma unroll
    for (int c = 0; c < 16; ++c) tot += red[c][t];
    const float4* xv = (const float4*)(x + bb * 8);
    float4 xa = xv[0], xb = xv[1];
    float xs8[8] = {xa.x, xa.y, xa.z, xa.w, xb.x, xb.y, xb.z, xb.w};
    float den = 1.0f;
#pragma unroll
    for (int i = 0; i < 8; ++i) {
      float rowsum = 0.0f;
#pragma unroll
      for (int q = 0; q < 4; ++q) {
        float s_ = fabsf(sigma[i * 4 + q]) + 1e-5f;
        float rs = __builtin_amdgcn_rcpf(s_);
        float nvq = -0.5f * rs * rs;
        float d = xs8[i] - mu[i * 4 + q];
        rowsum += __expf(d * d * nvq);
      }
      den *= rowsum;
    }
    out[bb] = tot / (den + 1e-6f);
  }
}

extern "C" void kernel_launch(void* const* d_in, const int* in_sizes, int n_in,
                              void* d_out, int out_size, void* d_ws, size_t ws_size,
                              hipStream_t stream) {
  const float* x     = (const float*)d_in[0];
  const float* mu    = (const float*)d_in[1];
  const float* sigma = (const float*)d_in[2];
  const float* cw    = (const float*)d_in[3];
  const float* cb    = (const float*)d_in[4];
  float* part = (float*)d_ws;       // 256 * 1024 floats = 1 MB
  float* out = (float*)d_out;

  anfis_main<<<NMTILE * 32, 512, 0, stream>>>(x, mu, sigma, cw, cb, part);
  anfis_final<<<NBATCH / 16, 256, 0, stream>>>(part, x, mu, sigma, out);
}

// Round 10
// 16.664 us; speedup vs baseline: 1.1467x; 1.1467x over previous
//
#include <hip/hip_runtime.h>

typedef _Float16 half2v __attribute__((ext_vector_type(2)));
typedef _Float16 half8v __attribute__((ext_vector_type(8)));
typedef float floatx4 __attribute__((ext_vector_type(4)));

#define NBATCH 1024
#define NKSPLIT 128
#define KPW 16            // k-steps (of 32 rules) per ksplit
#define NMTILE 16         // 16 mtiles x 64 batches
#define MSPAD 36          // LDS row stride (floats): 16B-aligned, 2-way-bank (free)
#define NPART 32          // part rows = one per block (4 ksplits pre-reduced)

__device__ __forceinline__ float sel4(float a0, float a1, float a2, float a3, int d) {
  float r = (d == 1) ? a1 : a0;
  r = (d == 2) ? a2 : r;
  r = (d == 3) ? a3 : r;
  return r;
}

__device__ __forceinline__ half2v cvt2h(float a, float b) {
  return __builtin_bit_cast(half2v, __builtin_amdgcn_cvt_pkrtz(a, b));
}

// ---- main: 256-thread block = 4 waves = 4 consecutive ksplits of one mtile.
// Block cooperatively computes the mtile's 64x32 memberships once into LDS,
// and block-reduces the 4 waves' partial sums before writing ONE part row.
// grid = 16 mtiles x 32 ksplit-quads = 512 blocks.
__global__ __launch_bounds__(256, 2) void anfis_main(
    const float* __restrict__ x, const float* __restrict__ mu,
    const float* __restrict__ sigma, const float* __restrict__ cw,
    const float* __restrict__ cb, float* __restrict__ part) {
  const int bid = blockIdx.x;
  const int mtile = bid >> 5;            // 0..15
  const int kq = bid & 31;               // 0..31
  const int t = threadIdx.x;
  const int w = t >> 6;                  // wave 0..3
  const int l = t & 63;
  const int g = l >> 4, col = l & 15;
  const int u = g & 1, h = g >> 1;
  const int ksplit = kq * 4 + w;
  const int d0 = (ksplit >> 5) & 3, d1 = (ksplit >> 3) & 3, d2 = (ksplit >> 1) & 3;
  const int d3h = ksplit & 1;
  const int b0 = mtile * 64;
  const int r0 = ksplit * (KPW * 32) + g * 8;

  // per-lane B gather base + strides. col>8 lanes mirror col==8 (cb broadcast);
  // their C columns are discarded by xc=0 in the epilogue.
  const bool isw = (col < 8);
  const float* gp = isw ? (cw + (size_t)r0 * 8 + col) : (cb + r0);
  const int es = isw ? 8 : 1;
  const int ks = isw ? 256 : 32;

  // prefetch first 4 k-steps of B (latency hides under the exp/LDS prologue)
  float fv[4][8];
#pragma unroll
  for (int kk = 0; kk < 4; ++kk)
#pragma unroll
    for (int e = 0; e < 8; ++e)
      fv[kk][e] = gp[kk * ks + e * es];

  // ---- cooperative membership fill: 2048 exps / 256 threads = 8 each
  __shared__ float msL[64][MSPAD];
  __shared__ float bsum[4][64];
  {
    const int bt = t >> 2;               // batch 0..63
    const int j0 = (t & 3) * 8;          // 8 js per thread
#pragma unroll
    for (int j = 0; j < 8; ++j) {
      const int jj = j0 + j;
      const int i = jj >> 2;
      float s_ = fabsf(sigma[jj]) + 1e-5f;       // uniform -> s_load
      float rs = __builtin_amdgcn_rcpf(s_);
      float nv = -0.5f * rs * rs;
      float d = x[(b0 + bt) * 8 + i] - mu[jj];   // mu uniform
      msL[bt][jj] = __expf(d * d * nv);
    }
  }
  __syncthreads();

  // ---- per-rowblock context from LDS
  half2v tab[4][4];
  float pA[4][2], pB[4][2];   // pre*m3{a,b} * m5{A,B}
  floatx4 m4v[4];
#pragma unroll
  for (int rb = 0; rb < 4; ++rb) {
    const float* row = msL[rb * 16 + col];
    floatx4 m0 = *(const floatx4*)(row + 0);
    floatx4 m1 = *(const floatx4*)(row + 4);
    floatx4 m2 = *(const floatx4*)(row + 8);
    floatx4 m3 = *(const floatx4*)(row + 12);
    floatx4 m4 = *(const floatx4*)(row + 16);
    floatx4 m5 = *(const floatx4*)(row + 20);
    floatx4 m6 = *(const floatx4*)(row + 24);
    floatx4 m7 = *(const floatx4*)(row + 28);
    float pre = sel4(m0[0], m0[1], m0[2], m0[3], d0) *
                sel4(m1[0], m1[1], m1[2], m1[3], d1) *
                sel4(m2[0], m2[1], m2[2], m2[3], d2);
    float m3a = d3h ? m3[2] : m3[0];
    float m3b = d3h ? m3[3] : m3[1];
    float m5A = h ? m5[1] : m5[0];
    float m5B = h ? m5[3] : m5[2];
    float m60 = u ? m6[2] : m6[0];
    float m61 = u ? m6[3] : m6[1];
    tab[rb][0] = cvt2h(m60 * m7[0], m60 * m7[1]);
    tab[rb][1] = cvt2h(m60 * m7[2], m60 * m7[3]);
    tab[rb][2] = cvt2h(m61 * m7[0], m61 * m7[1]);
    tab[rb][3] = cvt2h(m61 * m7[2], m61 * m7[3]);
    float t3a = pre * m3a, t3b = pre * m3b;
    pA[rb][0] = t3a * m5A; pA[rb][1] = t3a * m5B;
    pB[rb][0] = t3b * m5A; pB[rb][1] = t3b * m5B;
    m4v[rb] = m4;
  }

  floatx4 acc[4];
#pragma unroll
  for (int rb = 0; rb < 4; ++rb) acc[rb] = (floatx4){0.f, 0.f, 0.f, 0.f};

#pragma unroll
  for (int kk = 0; kk < KPW; ++kk) {
    const int j3 = kk >> 3, j4 = (kk >> 1) & 3, j01 = kk & 1;
    half2v b01 = cvt2h(fv[kk & 3][0], fv[kk & 3][1]);
    half2v b23 = cvt2h(fv[kk & 3][2], fv[kk & 3][3]);
    half2v b45 = cvt2h(fv[kk & 3][4], fv[kk & 3][5]);
    half2v b67 = cvt2h(fv[kk & 3][6], fv[kk & 3][7]);
    half8v b8 = {b01.x, b01.y, b23.x, b23.y, b45.x, b45.y, b67.x, b67.y};
    if (kk + 4 < KPW) {
#pragma unroll
      for (int e = 0; e < 8; ++e)
        fv[kk & 3][e] = gp[(kk + 4) * ks + e * es];
    }
#pragma unroll
    for (int rb = 0; rb < 4; ++rb) {
      float p5 = (j3 ? pB[rb][j01] : pA[rb][j01]) * m4v[rb][j4];
      _Float16 ph = (_Float16)p5;
      half2v ppv = {ph, ph};
      half2v a0 = ppv * tab[rb][0], a1 = ppv * tab[rb][1],
             a2 = ppv * tab[rb][2], a3 = ppv * tab[rb][3];
      half8v a8 = {a0.x, a0.y, a1.x, a1.y, a2.x, a2.y, a3.x, a3.y};
      acc[rb] = __builtin_amdgcn_mfma_f32_16x16x32_f16(a8, b8, acc[rb], 0, 0, 0);
    }
  }

  // epilogue: C[row=g*4+i][col], fold x, reduce over 16 cols -> LDS
#pragma unroll
  for (int rb = 0; rb < 4; ++rb) {
#pragma unroll
    for (int i = 0; i < 4; ++i) {
      int bb = b0 + rb * 16 + g * 4 + i;
      float xc = 0.0f;
      if (col < 8) xc = x[bb * 8 + col];
      else if (col == 8) xc = 1.0f;
      float v = acc[rb][i] * xc;
      v += __shfl_xor(v, 1);
      v += __shfl_xor(v, 2);
      v += __shfl_xor(v, 4);
      v += __shfl_xor(v, 8);
      if (col == 0) bsum[w][rb * 16 + g * 4 + i] = v;
    }
  }
  __syncthreads();

  // block-reduce the 4 waves' sums -> one coalesced part row per block
  if (t < 64) {
    float tot = bsum[0][t] + bsum[1][t] + bsum[2][t] + bsum[3][t];
    part[kq * NBATCH + b0 + t] = tot;
  }
}

// ---- final: 16 blocks x 64 lanes; 32 coalesced row reads + analytic denominator
__global__ __launch_bounds__(64) void anfis_final(
    const float* __restrict__ part, const float* __restrict__ x,
    const float* __restrict__ mu, const float* __restrict__ sigma,
    float* __restrict__ out) {
  const int b = blockIdx.x * 64 + threadIdx.x;

  float s = 0.0f;
#pragma unroll
  for (int j = 0; j < NPART; ++j)
    s += part[j * NBATCH + b];          // coalesced across lanes per row

  const float4* xv = (const float4*)(x + b * 8);
  float4 xa = xv[0], xb = xv[1];
  float xs8[8] = {xa.x, xa.y, xa.z, xa.w, xb.x, xb.y, xb.z, xb.w};
  float den = 1.0f;
#pragma unroll
  for (int i = 0; i < 8; ++i) {
    float rowsum = 0.0f;
#pragma unroll
    for (int q = 0; q < 4; ++q) {
      float s_ = fabsf(sigma[i * 4 + q]) + 1e-5f;
      float rs = __builtin_amdgcn_rcpf(s_);
      float nvq = -0.5f * rs * rs;
      float d = xs8[i] - mu[i * 4 + q];
      rowsum += __expf(d * d * nvq);
    }
    den *= rowsum;
  }
  out[b] = s / (den + 1e-6f);
}

extern "C" void kernel_launch(void* const* d_in, const int* in_sizes, int n_in,
                              void* d_out, int out_size, void* d_ws, size_t ws_size,
                              hipStream_t stream) {
  const float* x     = (const float*)d_in[0];
  const float* mu    = (const float*)d_in[1];
  const float* sigma = (const float*)d_in[2];
  const float* cw    = (const float*)d_in[3];
  const float* cb    = (const float*)d_in[4];
  float* part = (float*)d_ws;       // 32 * 1024 floats = 128 KB
  float* out = (float*)d_out;

  anfis_main<<<NMTILE * 32, 256, 0, stream>>>(x, mu, sigma, cw, cb, part);
  anfis_final<<<NBATCH / 64, 64, 0, stream>>>(part, x, mu, sigma, out);
}